// Round 4
// baseline (729.905 us; speedup 1.0000x reference)
//
#include <hip/hip_runtime.h>
#include <math.h>

#define NN 1024
#define DD 128
#define HH 8

typedef __attribute__((ext_vector_type(8))) short short8;
typedef __attribute__((ext_vector_type(4))) short short4v;
typedef __attribute__((ext_vector_type(4))) float f32x4;

__device__ inline unsigned short f2bf(float x) {
    union { float f; unsigned u; } v; v.f = x;
    return (unsigned short)((v.u + 0x7FFF + ((v.u >> 16) & 1)) >> 16);
}
__device__ inline unsigned pack2(float a, float b) {
    return (unsigned)f2bf(a) | ((unsigned)f2bf(b) << 16);
}

// ---------------- prep: W transposes (bf16) + WoG = Wo@Wg fold ---------------
__global__ __launch_bounds__(256) void k_prep(
    const float* __restrict__ Wq, const float* __restrict__ Wk, const float* __restrict__ Wv,
    const float* __restrict__ Wo, const float* __restrict__ Wg, const float* __restrict__ bo,
    unsigned short* WqT, unsigned short* WkT, unsigned short* WvT,
    unsigned short* WoGT, float* boG) {
    int id = blockIdx.x, tid = threadIdx.x;
    if (id < 384) {
        const float* src; unsigned short* dst; int ti;
        if (id < 128)      { src = Wq; dst = WqT; ti = id; }
        else if (id < 256) { src = Wk; dst = WkT; ti = id - 128; }
        else               { src = Wv; dst = WvT; ti = id - 256; }
        int r0 = (ti >> 5) << 5, c0 = (ti & 31) << 5;   // R=128, C=1024
        __shared__ float T[32][33];
        int r = tid >> 3, c4 = (tid & 7) << 2;
        float4 v = *(const float4*)&src[(size_t)(r0 + r) * 1024 + c0 + c4];
        T[r][c4] = v.x; T[r][c4 + 1] = v.y; T[r][c4 + 2] = v.z; T[r][c4 + 3] = v.w;
        __syncthreads();
        int c = tid >> 3, r4 = (tid & 7) << 2;
        uint2 o;
        o.x = pack2(T[r4][c], T[r4 + 1][c]);
        o.y = pack2(T[r4 + 2][c], T[r4 + 3][c]);
        *(uint2*)&dst[(size_t)(c0 + c) * 128 + r0 + r4] = o;
    } else {
        int kb8 = id - 384;                 // k rows [kb8*8, kb8*8+8)
        int c = tid & 127, kk0 = tid >> 7;
        for (int kk = kk0; kk < 8; kk += 2) {
            int k = kb8 * 8 + kk;
            float s = 0.f;
#pragma unroll 8
            for (int d = 0; d < 128; ++d) s += Wo[k * 128 + d] * Wg[d * 128 + c];
            WoGT[(size_t)c * 1024 + k] = f2bf(s);
        }
        if (kb8 == 0 && tid < 128) {
            float s = 0.f;
            for (int d = 0; d < 128; ++d) s += bo[d] * Wg[d * 128 + tid];
            boG[tid] = s;
        }
    }
}

// ---------------- K1: c = bf16(F_c + emb) ------------------------------------
__global__ __launch_bounds__(256) void k_embed(const float* __restrict__ F_c,
                                               const int* __restrict__ t,
                                               unsigned short* __restrict__ cb) {
    int gi = blockIdx.x * 256 + threadIdx.x;
    int row = gi >> 4, ch = gi & 15;
    int b = row >> 10, n = row & 1023;
    float tv = (float)t[b];
    int j = n & 511;
    float e = tv * expf(-(float)j * 0.013518112092919054f);
    float emb = (n < 512) ? sinf(e) : cosf(e);
    const float* src = F_c + (size_t)row * 128 + ch * 8;
    float4 a = *(const float4*)src;
    float4 c4 = *(const float4*)(src + 4);
    uint4 o;
    o.x = pack2(a.x + emb, a.y + emb);  o.y = pack2(a.z + emb, a.w + emb);
    o.z = pack2(c4.x + emb, c4.y + emb); o.w = pack2(c4.z + emb, c4.w + emb);
    *(uint4*)&cb[(size_t)row * 128 + ch * 8] = o;
}

// ---------------- QKV projection: K=128 MFMA GEMM, 128x128 tile --------------
__global__ __launch_bounds__(256) void k_proj(const unsigned short* __restrict__ Ain,
                                              const unsigned short* __restrict__ WT,
                                              const float* __restrict__ bias,
                                              unsigned short* __restrict__ Out,
                                              float scale, int mode) {
    __shared__ __align__(16) unsigned short sm[2 * 128 * 136];
    unsigned short* CT  = sm;
    unsigned short* WTs = sm + 128 * 136;
    int tid = threadIdx.x;
    int m0 = blockIdx.x * 128;
    int head = blockIdx.y;
    int w = tid >> 6, lane = tid & 63, n16 = lane & 15, quad = lane >> 4;
#pragma unroll
    for (int p = 0; p < 8; ++p) {
        int idx = tid + p * 256;
        int r = idx >> 4, ch = idx & 15;
        *(uint4*)&CT[r * 136 + ch * 8]  = *(const uint4*)&Ain[(size_t)(m0 + r) * 128 + ch * 8];
        *(uint4*)&WTs[r * 136 + ch * 8] = *(const uint4*)&WT[(size_t)(head * 128 + r) * 128 + ch * 8];
    }
    __syncthreads();
    int wr = (w >> 1) * 64, wc = (w & 1) * 64;
    f32x4 acc[4][4];
#pragma unroll
    for (int i = 0; i < 4; i++)
#pragma unroll
        for (int j = 0; j < 4; j++) acc[i][j] = (f32x4){0.f, 0.f, 0.f, 0.f};
#pragma unroll
    for (int kk = 0; kk < 4; ++kk) {
        short8 af[4], bf[4];
#pragma unroll
        for (int rb = 0; rb < 4; ++rb)
            af[rb] = *(const short8*)&CT[(wr + rb * 16 + n16) * 136 + kk * 32 + quad * 8];
#pragma unroll
        for (int cb = 0; cb < 4; ++cb)
            bf[cb] = *(const short8*)&WTs[(wc + cb * 16 + n16) * 136 + kk * 32 + quad * 8];
#pragma unroll
        for (int rb = 0; rb < 4; ++rb)
#pragma unroll
            for (int cb = 0; cb < 4; ++cb)
                acc[rb][cb] = __builtin_amdgcn_mfma_f32_16x16x32_bf16(af[rb], bf[cb], acc[rb][cb], 0, 0, 0);
    }
    __syncthreads();
#pragma unroll
    for (int rb = 0; rb < 4; ++rb)
#pragma unroll
        for (int cb = 0; cb < 4; ++cb) {
            int colb = wc + cb * 16 + n16;
            float bs = bias[head * 128 + colb];
#pragma unroll
            for (int reg = 0; reg < 4; ++reg) {
                int rowb = wr + rb * 16 + quad * 4 + reg;
                unsigned short val = f2bf((acc[rb][cb][reg] + bs) * scale);
                if (mode == 0) CT[rowb * 136 + colb] = val;
                else           CT[colb * 136 + rowb] = val;
            }
        }
    __syncthreads();
    int b = m0 >> 10, n0 = m0 & 1023;
    size_t base = (size_t)(b * 8 + head) * 131072;
    if (mode == 0) {
#pragma unroll
        for (int p = 0; p < 8; ++p) {
            int idx = tid + p * 256;
            int r = idx >> 4, ch = idx & 15;
            *(uint4*)&Out[base + (size_t)(n0 + r) * 128 + ch * 8] = *(const uint4*)&CT[r * 136 + ch * 8];
        }
    } else {
#pragma unroll
        for (int p = 0; p < 8; ++p) {
            int idx = tid + p * 256;
            int r = idx >> 4, ch = idx & 15;
            *(uint4*)&Out[base + (size_t)r * 1024 + n0 + ch * 8] = *(const uint4*)&CT[r * 136 + ch * 8];
        }
    }
}

// ---------------- attention: 36 KB LDS (Sp aliases Ks), 4 blocks/CU ----------
__global__ __launch_bounds__(256, 4) void k_attn3(const unsigned short* __restrict__ qb,
                                                  const unsigned short* __restrict__ kb,
                                                  const unsigned short* __restrict__ vtb,
                                                  unsigned short* __restrict__ ctxb) {
    __shared__ __align__(16) unsigned short sm[17920];
    unsigned short* Ks = sm;            // [64][136] = 8704 shorts
    unsigned short* Vt = sm + 8704;     // [128][72] = 9216 shorts
    unsigned short* Sp = sm;            // alias of Ks: per-wave [32][68]

    const int tid = threadIdx.x;
    const int w = tid >> 6, lane = tid & 63;
    const int n16 = lane & 15, quad = lane >> 4;
    const int g = blockIdx.x;
    const int bh = g >> 3, tileq = g & 7;

    const unsigned short* Qp = qb + (size_t)bh * 131072 + (size_t)tileq * 128 * 128;
    const unsigned short* Kp = kb + (size_t)bh * 131072;
    const unsigned short* Vp = vtb + (size_t)bh * 131072;

    short8 qf[2][4];
#pragma unroll
    for (int rb = 0; rb < 2; ++rb)
#pragma unroll
        for (int dc = 0; dc < 4; ++dc)
            qf[rb][dc] = *(const short8*)&Qp[(size_t)(w * 32 + rb * 16 + n16) * 128 + dc * 32 + quad * 8];

    float mrun[2][4], lrun[2][4];
#pragma unroll
    for (int rb = 0; rb < 2; ++rb)
#pragma unroll
        for (int r = 0; r < 4; ++r) { mrun[rb][r] = -1e30f; lrun[rb][r] = 0.f; }
    f32x4 O[2][8];
#pragma unroll
    for (int rb = 0; rb < 2; ++rb)
#pragma unroll
        for (int dc = 0; dc < 8; ++dc) O[rb][dc] = (f32x4){0.f, 0.f, 0.f, 0.f};

    for (int kt = 0; kt < 16; ++kt) {
        __syncthreads();                 // prev PV (Sp,Vt reads) done
#pragma unroll
        for (int p = 0; p < 4; ++p) {    // K tile 64x128
            int idx = tid + p * 256;
            int r = idx >> 4, ch = idx & 15;
            *(uint4*)&Ks[r * 136 + ch * 8] = *(const uint4*)&Kp[(size_t)(kt * 64 + r) * 128 + ch * 8];
        }
#pragma unroll
        for (int p = 0; p < 4; ++p) {    // V^T tile 128x64
            int idx = tid + p * 256;
            int r = idx >> 3, ch = idx & 7;
            *(uint4*)&Vt[r * 72 + ch * 8] = *(const uint4*)&Vp[(size_t)r * 1024 + kt * 64 + ch * 8];
        }
        __syncthreads();                 // staged

        f32x4 S[2][4];
#pragma unroll
        for (int rb = 0; rb < 2; ++rb)
#pragma unroll
            for (int kc = 0; kc < 4; ++kc) S[rb][kc] = (f32x4){0.f, 0.f, 0.f, 0.f};
#pragma unroll
        for (int kc = 0; kc < 4; ++kc)
#pragma unroll
            for (int dc = 0; dc < 4; ++dc) {
                short8 kf = *(const short8*)&Ks[(kc * 16 + n16) * 136 + dc * 32 + quad * 8];
                S[0][kc] = __builtin_amdgcn_mfma_f32_16x16x32_bf16(qf[0][dc], kf, S[0][kc], 0, 0, 0);
                S[1][kc] = __builtin_amdgcn_mfma_f32_16x16x32_bf16(qf[1][dc], kf, S[1][kc], 0, 0, 0);
            }

        float alpha[2][4];
#pragma unroll
        for (int rb = 0; rb < 2; ++rb)
#pragma unroll
            for (int reg = 0; reg < 4; ++reg) {
                float mx = fmaxf(fmaxf(S[rb][0][reg], S[rb][1][reg]), fmaxf(S[rb][2][reg], S[rb][3][reg]));
                mx = fmaxf(mx, __shfl_xor(mx, 1));
                mx = fmaxf(mx, __shfl_xor(mx, 2));
                mx = fmaxf(mx, __shfl_xor(mx, 4));
                mx = fmaxf(mx, __shfl_xor(mx, 8));
                float mnew = fmaxf(mrun[rb][reg], mx);
                alpha[rb][reg] = __expf(mrun[rb][reg] - mnew);
                mrun[rb][reg] = mnew;
                float ps = 0.f;
#pragma unroll
                for (int kc = 0; kc < 4; ++kc) {
                    float p = __expf(S[rb][kc][reg] - mnew);
                    S[rb][kc][reg] = p;
                    ps += p;
                }
                ps += __shfl_xor(ps, 1);
                ps += __shfl_xor(ps, 2);
                ps += __shfl_xor(ps, 4);
                ps += __shfl_xor(ps, 8);
                lrun[rb][reg] = lrun[rb][reg] * alpha[rb][reg] + ps;
            }

        __syncthreads();                 // all Ks reads done -> safe to alias Sp
#pragma unroll
        for (int rb = 0; rb < 2; ++rb)
#pragma unroll
            for (int kc = 0; kc < 4; ++kc)
#pragma unroll
                for (int reg = 0; reg < 4; ++reg)
                    Sp[w * 2176 + (rb * 16 + quad * 4 + reg) * 68 + kc * 16 + n16] = f2bf(S[rb][kc][reg]);
        asm volatile("s_waitcnt lgkmcnt(0)" ::: "memory");   // own writes visible

#pragma unroll
        for (int rb = 0; rb < 2; ++rb)
#pragma unroll
            for (int dc = 0; dc < 8; ++dc)
#pragma unroll
                for (int reg = 0; reg < 4; ++reg) O[rb][dc][reg] *= alpha[rb][reg];
#pragma unroll
        for (int kchunk = 0; kchunk < 2; ++kchunk) {
            int off0 = w * 2176 + n16 * 68 + kchunk * 32 + quad * 8;
            short4v a0 = *(const short4v*)&Sp[off0];
            short4v b0 = *(const short4v*)&Sp[off0 + 4];
            short4v a1 = *(const short4v*)&Sp[off0 + 16 * 68];
            short4v b1 = *(const short4v*)&Sp[off0 + 16 * 68 + 4];
            short8 pf0, pf1;
#pragma unroll
            for (int j = 0; j < 4; ++j) {
                pf0[j] = a0[j]; pf0[j + 4] = b0[j];
                pf1[j] = a1[j]; pf1[j + 4] = b1[j];
            }
#pragma unroll
            for (int dc = 0; dc < 8; ++dc) {
                short8 vf = *(const short8*)&Vt[(dc * 16 + n16) * 72 + kchunk * 32 + quad * 8];
                O[0][dc] = __builtin_amdgcn_mfma_f32_16x16x32_bf16(pf0, vf, O[0][dc], 0, 0, 0);
                O[1][dc] = __builtin_amdgcn_mfma_f32_16x16x32_bf16(pf1, vf, O[1][dc], 0, 0, 0);
            }
        }
    }

    __syncthreads();
    unsigned short* Ct = sm;    // [128][136]
#pragma unroll
    for (int rb = 0; rb < 2; ++rb)
#pragma unroll
        for (int reg = 0; reg < 4; ++reg) {
            float inv = 1.f / lrun[rb][reg];
            int row = w * 32 + rb * 16 + quad * 4 + reg;
#pragma unroll
            for (int dc = 0; dc < 8; ++dc)
                Ct[row * 136 + dc * 16 + n16] = f2bf(O[rb][dc][reg] * inv);
        }
    __syncthreads();
    unsigned short* Outp = ctxb + (size_t)bh * 131072 + (size_t)tileq * 128 * 128;
#pragma unroll
    for (int p = 0; p < 8; ++p) {
        int idx = tid + p * 256;
        int r = idx >> 4, ch = idx & 15;
        *(uint4*)&Outp[(size_t)r * 128 + ch * 8] = *(const uint4*)&Ct[r * 136 + ch * 8];
    }
}

// ---------------- hgT = (ctx @ WoG + boG)^T  (K=1024, Wg folded) -------------
__global__ __launch_bounds__(256) void k_proj_og(const unsigned short* __restrict__ Ctxb,
                                                 const unsigned short* __restrict__ WoGT,
                                                 const float* __restrict__ boG,
                                                 unsigned short* __restrict__ HgT) {
    __shared__ __align__(16) unsigned short sm[64 * 72 + 128 * 72];
    unsigned short* As = sm;
    unsigned short* Bs = sm + 64 * 72;
    int tid = threadIdx.x;
    int m0 = blockIdx.x * 64;
    int b = m0 >> 10, n0 = m0 & 1023;
    int w = tid >> 6, lane = tid & 63, n16 = lane & 15, quad = lane >> 4;
    int wr = (w & 1) * 32, wc = (w >> 1) * 64;
    f32x4 acc[2][4];
#pragma unroll
    for (int i = 0; i < 2; i++)
#pragma unroll
        for (int j = 0; j < 4; j++) acc[i][j] = (f32x4){0.f, 0.f, 0.f, 0.f};
    for (int kt = 0; kt < 16; ++kt) {
        __syncthreads();
        int hh = kt >> 1, d0 = (kt & 1) * 64;
#pragma unroll
        for (int p = 0; p < 2; ++p) {
            int idx = tid + p * 256;
            int r = idx >> 3, ch = idx & 7;
            *(uint4*)&As[r * 72 + ch * 8] =
                *(const uint4*)&Ctxb[((size_t)(b * 8 + hh) * 1024 + n0 + r) * 128 + d0 + ch * 8];
        }
#pragma unroll
        for (int p = 0; p < 4; ++p) {
            int idx = tid + p * 256;
            int r = idx >> 3, ch = idx & 7;
            *(uint4*)&Bs[r * 72 + ch * 8] = *(const uint4*)&WoGT[(size_t)r * 1024 + kt * 64 + ch * 8];
        }
        __syncthreads();
#pragma unroll
        for (int kk = 0; kk < 2; ++kk) {
            short8 af0 = *(const short8*)&As[(wr + n16) * 72 + kk * 32 + quad * 8];
            short8 af1 = *(const short8*)&As[(wr + 16 + n16) * 72 + kk * 32 + quad * 8];
#pragma unroll
            for (int cb = 0; cb < 4; ++cb) {
                short8 bf = *(const short8*)&Bs[(wc + cb * 16 + n16) * 72 + kk * 32 + quad * 8];
                acc[0][cb] = __builtin_amdgcn_mfma_f32_16x16x32_bf16(af0, bf, acc[0][cb], 0, 0, 0);
                acc[1][cb] = __builtin_amdgcn_mfma_f32_16x16x32_bf16(af1, bf, acc[1][cb], 0, 0, 0);
            }
        }
    }
    __syncthreads();
    unsigned short* Ct = sm;    // [128 cols][80]
#pragma unroll
    for (int rb = 0; rb < 2; ++rb)
#pragma unroll
        for (int cb = 0; cb < 4; ++cb) {
            int col = wc + cb * 16 + n16;
            float bs = boG[col];
#pragma unroll
            for (int reg = 0; reg < 4; ++reg)
                Ct[col * 80 + wr + rb * 16 + quad * 4 + reg] = f2bf(acc[rb][cb][reg] + bs);
        }
    __syncthreads();
#pragma unroll
    for (int p = 0; p < 4; ++p) {
        int idx = tid + p * 256;
        int c = idx >> 3, ch = idx & 7;
        *(uint4*)&HgT[(size_t)b * 131072 + (size_t)c * 1024 + n0 + ch * 8] =
            *(const uint4*)&Ct[c * 80 + ch * 8];
    }
}

// ---------------- feat = relu(A_t @ hg) fused with row-normalize -> bf16 -----
__global__ __launch_bounds__(256) void k_at_norm(const float* __restrict__ At,
                                                 const unsigned short* __restrict__ HgT,
                                                 unsigned short* __restrict__ Nb) {
    __shared__ __align__(16) char smc[64 * 136 * 4];
    unsigned short* As = (unsigned short*)smc;            // [64][72]
    unsigned short* Bs = (unsigned short*)smc + 64 * 72;  // [128][72]
    int tid = threadIdx.x;
    int bz = blockIdx.z;
    int m0 = blockIdx.x * 64;
    int w = tid >> 6, lane = tid & 63, n16 = lane & 15, quad = lane >> 4;
    int wr = (w & 1) * 32, wc = (w >> 1) * 64;
    f32x4 acc[2][4];
#pragma unroll
    for (int i = 0; i < 2; i++)
#pragma unroll
        for (int j = 0; j < 4; j++) acc[i][j] = (f32x4){0.f, 0.f, 0.f, 0.f};
    for (int kt = 0; kt < 16; ++kt) {
        __syncthreads();
#pragma unroll
        for (int p = 0; p < 2; ++p) {
            int idx = tid + p * 256;
            int r = idx >> 3, ch = idx & 7;
            const float* s = At + (size_t)bz * 1048576 + (size_t)(m0 + r) * 1024 + kt * 64 + ch * 8;
            float4 x = *(const float4*)s;
            float4 y = *(const float4*)(s + 4);
            uint4 o;
            o.x = pack2(x.x, x.y); o.y = pack2(x.z, x.w);
            o.z = pack2(y.x, y.y); o.w = pack2(y.z, y.w);
            *(uint4*)&As[r * 72 + ch * 8] = o;
        }
#pragma unroll
        for (int p = 0; p < 4; ++p) {
            int idx = tid + p * 256;
            int r = idx >> 3, ch = idx & 7;
            *(uint4*)&Bs[r * 72 + ch * 8] =
                *(const uint4*)&HgT[(size_t)bz * 131072 + (size_t)r * 1024 + kt * 64 + ch * 8];
        }
        __syncthreads();
#pragma unroll
        for (int kk = 0; kk < 2; ++kk) {
            short8 af0 = *(const short8*)&As[(wr + n16) * 72 + kk * 32 + quad * 8];
            short8 af1 = *(const short8*)&As[(wr + 16 + n16) * 72 + kk * 32 + quad * 8];
#pragma unroll
            for (int cb = 0; cb < 4; ++cb) {
                short8 bf = *(const short8*)&Bs[(wc + cb * 16 + n16) * 72 + kk * 32 + quad * 8];
                acc[0][cb] = __builtin_amdgcn_mfma_f32_16x16x32_bf16(af0, bf, acc[0][cb], 0, 0, 0);
                acc[1][cb] = __builtin_amdgcn_mfma_f32_16x16x32_bf16(af1, bf, acc[1][cb], 0, 0, 0);
            }
        }
    }
    __syncthreads();
    float* F = (float*)smc;    // [64][136]
#pragma unroll
    for (int rb = 0; rb < 2; ++rb)
#pragma unroll
        for (int cb = 0; cb < 4; ++cb) {
            int col = wc + cb * 16 + n16;
#pragma unroll
            for (int reg = 0; reg < 4; ++reg)
                F[(wr + rb * 16 + quad * 4 + reg) * 136 + col] = fmaxf(acc[rb][cb][reg], 0.f);
        }
    __syncthreads();
    // normalize: 4 lanes per row, 32 cols each
    int r = tid >> 2, l4 = tid & 3;
    float vals[32];
    float s = 0.f;
#pragma unroll
    for (int u = 0; u < 32; ++u) { vals[u] = F[r * 136 + l4 * 32 + u]; s += vals[u]; }
    s += __shfl_xor(s, 1);
    s += __shfl_xor(s, 2);
    float mu = s * (1.f / 128.f);
    float sq = 0.f;
#pragma unroll
    for (int u = 0; u < 32; ++u) { float d = vals[u] - mu; vals[u] = d; sq += d * d; }
    sq += __shfl_xor(sq, 1);
    sq += __shfl_xor(sq, 2);
    float inv = 1.f / (sqrtf(sq * (1.f / 127.f)) + 1e-8f);
    size_t rowb = ((size_t)bz * 1024 + m0 + r) * 128 + l4 * 32;
#pragma unroll
    for (int gch = 0; gch < 4; ++gch) {
        uint4 o;
        o.x = pack2(vals[gch * 8 + 0] * inv, vals[gch * 8 + 1] * inv);
        o.y = pack2(vals[gch * 8 + 2] * inv, vals[gch * 8 + 3] * inv);
        o.z = pack2(vals[gch * 8 + 4] * inv, vals[gch * 8 + 5] * inv);
        o.w = pack2(vals[gch * 8 + 6] * inv, vals[gch * 8 + 7] * inv);
        *(uint4*)&Nb[rowb + gch * 8] = o;
    }
}

// ---------------- out[b] = norm @ norm^T / 128, LDS-bounced stores -----------
__global__ __launch_bounds__(256) void k_corr(const unsigned short* __restrict__ Nb,
                                              float* __restrict__ Out) {
    __shared__ __align__(16) unsigned short sm[2 * 128 * 136];
    unsigned short* Ar = sm;
    unsigned short* Br = sm + 128 * 136;
    int tid = threadIdx.x;
    int bz = blockIdx.z;
    int n0 = blockIdx.x * 128, m0 = blockIdx.y * 128;
    const unsigned short* base = Nb + (size_t)bz * 131072;
    int w = tid >> 6, lane = tid & 63, n16 = lane & 15, quad = lane >> 4;
#pragma unroll
    for (int p = 0; p < 8; ++p) {
        int idx = tid + p * 256;
        int r = idx >> 4, ch = idx & 15;
        *(uint4*)&Ar[r * 136 + ch * 8] = *(const uint4*)&base[(size_t)(n0 + r) * 128 + ch * 8];
        *(uint4*)&Br[r * 136 + ch * 8] = *(const uint4*)&base[(size_t)(m0 + r) * 128 + ch * 8];
    }
    __syncthreads();
    int wr = (w >> 1) * 64, wc = (w & 1) * 64;
    f32x4 acc[4][4];
#pragma unroll
    for (int i = 0; i < 4; i++)
#pragma unroll
        for (int j = 0; j < 4; j++) acc[i][j] = (f32x4){0.f, 0.f, 0.f, 0.f};
#pragma unroll
    for (int kk = 0; kk < 4; ++kk) {
        short8 af[4], bf[4];
#pragma unroll
        for (int rb = 0; rb < 4; ++rb)
            af[rb] = *(const short8*)&Ar[(wr + rb * 16 + n16) * 136 + kk * 32 + quad * 8];
#pragma unroll
        for (int cb = 0; cb < 4; ++cb)
            bf[cb] = *(const short8*)&Br[(wc + cb * 16 + n16) * 136 + kk * 32 + quad * 8];
#pragma unroll
        for (int rb = 0; rb < 4; ++rb)
#pragma unroll
            for (int cb = 0; cb < 4; ++cb)
                acc[rb][cb] = __builtin_amdgcn_mfma_f32_16x16x32_bf16(af[rb], bf[cb], acc[rb][cb], 0, 0, 0);
    }
    __syncthreads();
    float* F = (float*)sm;   // [64][136] fp32 bounce, two row-passes
    float* Op = Out + (size_t)bz * 1048576;
#pragma unroll
    for (int pass = 0; pass < 2; ++pass) {
        if ((w >> 1) == pass) {
#pragma unroll
            for (int rb = 0; rb < 4; ++rb)
#pragma unroll
                for (int cb = 0; cb < 4; ++cb) {
                    int col = wc + cb * 16 + n16;
#pragma unroll
                    for (int reg = 0; reg < 4; ++reg)
                        F[(rb * 16 + quad * 4 + reg) * 136 + col] = acc[rb][cb][reg] * 0.0078125f;
                }
        }
        __syncthreads();
#pragma unroll
        for (int i = 0; i < 8; ++i) {
            int idx = tid + i * 256;
            int r = idx >> 5, ch = idx & 31;
            *(float4*)&Op[(size_t)(n0 + pass * 64 + r) * 1024 + m0 + ch * 4] =
                *(const float4*)&F[r * 136 + ch * 4];
        }
        __syncthreads();
    }
}

extern "C" void kernel_launch(void* const* d_in, const int* in_sizes, int n_in,
                              void* d_out, int out_size, void* d_ws, size_t ws_size,
                              hipStream_t stream) {
    const float* A_t = (const float*)d_in[0];
    const float* F_c = (const float*)d_in[1];
    const int*   t   = (const int*)d_in[2];
    const float* Wq  = (const float*)d_in[3];
    const float* bq  = (const float*)d_in[4];
    const float* Wk  = (const float*)d_in[5];
    const float* bk  = (const float*)d_in[6];
    const float* Wv  = (const float*)d_in[7];
    const float* bv  = (const float*)d_in[8];
    const float* Wo  = (const float*)d_in[9];
    const float* bo  = (const float*)d_in[10];
    const float* Wg  = (const float*)d_in[11];
    float* out = (float*)d_out;
    char* ws = (char*)d_ws;

    unsigned short* cb   = (unsigned short*)(ws);                 //  4 MB
    unsigned short* qb   = (unsigned short*)(ws + 4194304);       // 33.5 MB
    unsigned short* kbuf = (unsigned short*)(ws + 37748736);      // 33.5 MB
    unsigned short* vtb  = (unsigned short*)(ws + 71303168);      // 33.5 MB
    unsigned short* ctxb = (unsigned short*)(ws + 104857600);     // 33.5 MB
    unsigned short* hgT  = (unsigned short*)(ws + 138412032);     //  4 MB
    unsigned short* nb   = (unsigned short*)(ws + 142606336);     //  4 MB
    unsigned short* WqT  = (unsigned short*)(ws + 146800640);
    unsigned short* WkT  = (unsigned short*)(ws + 147062784);
    unsigned short* WvT  = (unsigned short*)(ws + 147324928);
    unsigned short* WoGT = (unsigned short*)(ws + 147587072);
    float*          boG  = (float*)         (ws + 147849216);

    const float qscale = 0.08838834764831845f;   // 1/sqrt(128)

    k_prep<<<512, 256, 0, stream>>>(Wq, Wk, Wv, Wo, Wg, bo, WqT, WkT, WvT, WoGT, boG);
    k_embed<<<1024, 256, 0, stream>>>(F_c, t, cb);
    k_proj<<<dim3(128, 8), 256, 0, stream>>>(cb, WqT, bq, qb,   qscale, 0);
    k_proj<<<dim3(128, 8), 256, 0, stream>>>(cb, WkT, bk, kbuf, 1.f,    0);
    k_proj<<<dim3(128, 8), 256, 0, stream>>>(cb, WvT, bv, vtb,  1.f,    1);
    k_attn3<<<1024, 256, 0, stream>>>(qb, kbuf, vtb, ctxb);
    k_proj_og<<<256, 256, 0, stream>>>(ctxb, WoGT, boG, hgT);
    k_at_norm<<<dim3(16, 1, 16), 256, 0, stream>>>(A_t, hgT, nb);
    k_corr<<<dim3(8, 8, 16), 256, 0, stream>>>(nb, out);
}

// Round 5
// 508.772 us; speedup vs baseline: 1.4346x; 1.4346x over previous
//
#include <hip/hip_runtime.h>
#include <math.h>

#define NN 1024
#define DD 128
#define HH 8

typedef __attribute__((ext_vector_type(8))) short short8;
typedef __attribute__((ext_vector_type(4))) short short4v;
typedef __attribute__((ext_vector_type(4))) float f32x4;

__device__ inline unsigned short f2bf(float x) {
    union { float f; unsigned u; } v; v.f = x;
    return (unsigned short)((v.u + 0x7FFF + ((v.u >> 16) & 1)) >> 16);
}
__device__ inline unsigned pack2(float a, float b) {
    return (unsigned)f2bf(a) | ((unsigned)f2bf(b) << 16);
}

// ---------------- prep: W transposes (bf16) + WoG = Wo@Wg fold ---------------
__global__ __launch_bounds__(256) void k_prep(
    const float* __restrict__ Wq, const float* __restrict__ Wk, const float* __restrict__ Wv,
    const float* __restrict__ Wo, const float* __restrict__ Wg, const float* __restrict__ bo,
    unsigned short* WqT, unsigned short* WkT, unsigned short* WvT,
    unsigned short* WoGT, float* boG) {
    int id = blockIdx.x, tid = threadIdx.x;
    if (id < 384) {
        const float* src; unsigned short* dst; int ti;
        if (id < 128)      { src = Wq; dst = WqT; ti = id; }
        else if (id < 256) { src = Wk; dst = WkT; ti = id - 128; }
        else               { src = Wv; dst = WvT; ti = id - 256; }
        int r0 = (ti >> 5) << 5, c0 = (ti & 31) << 5;   // R=128, C=1024
        __shared__ float T[32][33];
        int r = tid >> 3, c4 = (tid & 7) << 2;
        float4 v = *(const float4*)&src[(size_t)(r0 + r) * 1024 + c0 + c4];
        T[r][c4] = v.x; T[r][c4 + 1] = v.y; T[r][c4 + 2] = v.z; T[r][c4 + 3] = v.w;
        __syncthreads();
        int c = tid >> 3, r4 = (tid & 7) << 2;
        uint2 o;
        o.x = pack2(T[r4][c], T[r4 + 1][c]);
        o.y = pack2(T[r4 + 2][c], T[r4 + 3][c]);
        *(uint2*)&dst[(size_t)(c0 + c) * 128 + r0 + r4] = o;
    } else {
        int kb8 = id - 384;                 // k rows [kb8*8, kb8*8+8)
        int c = tid & 127, kk0 = tid >> 7;
        for (int kk = kk0; kk < 8; kk += 2) {
            int k = kb8 * 8 + kk;
            float s = 0.f;
#pragma unroll 8
            for (int d = 0; d < 128; ++d) s += Wo[k * 128 + d] * Wg[d * 128 + c];
            WoGT[(size_t)c * 1024 + k] = f2bf(s);
        }
        if (kb8 == 0 && tid < 128) {
            float s = 0.f;
            for (int d = 0; d < 128; ++d) s += bo[d] * Wg[d * 128 + tid];
            boG[tid] = s;
        }
    }
}

// ---------------- K1: c = bf16(F_c + emb) ------------------------------------
__global__ __launch_bounds__(256) void k_embed(const float* __restrict__ F_c,
                                               const int* __restrict__ t,
                                               unsigned short* __restrict__ cb) {
    int gi = blockIdx.x * 256 + threadIdx.x;
    int row = gi >> 4, ch = gi & 15;
    int b = row >> 10, n = row & 1023;
    float tv = (float)t[b];
    int j = n & 511;
    float e = tv * expf(-(float)j * 0.013518112092919054f);
    float emb = (n < 512) ? sinf(e) : cosf(e);
    const float* src = F_c + (size_t)row * 128 + ch * 8;
    float4 a = *(const float4*)src;
    float4 c4 = *(const float4*)(src + 4);
    uint4 o;
    o.x = pack2(a.x + emb, a.y + emb);  o.y = pack2(a.z + emb, a.w + emb);
    o.z = pack2(c4.x + emb, c4.y + emb); o.w = pack2(c4.z + emb, c4.w + emb);
    *(uint4*)&cb[(size_t)row * 128 + ch * 8] = o;
}

// ---------------- QKV projection: K=128 MFMA GEMM, 128x128 tile --------------
__global__ __launch_bounds__(256) void k_proj(const unsigned short* __restrict__ Ain,
                                              const unsigned short* __restrict__ WT,
                                              const float* __restrict__ bias,
                                              unsigned short* __restrict__ Out,
                                              float scale, int mode) {
    __shared__ __align__(16) unsigned short sm[2 * 128 * 136];
    unsigned short* CT  = sm;
    unsigned short* WTs = sm + 128 * 136;
    int tid = threadIdx.x;
    int m0 = blockIdx.x * 128;
    int head = blockIdx.y;
    int w = tid >> 6, lane = tid & 63, n16 = lane & 15, quad = lane >> 4;
#pragma unroll
    for (int p = 0; p < 8; ++p) {
        int idx = tid + p * 256;
        int r = idx >> 4, ch = idx & 15;
        *(uint4*)&CT[r * 136 + ch * 8]  = *(const uint4*)&Ain[(size_t)(m0 + r) * 128 + ch * 8];
        *(uint4*)&WTs[r * 136 + ch * 8] = *(const uint4*)&WT[(size_t)(head * 128 + r) * 128 + ch * 8];
    }
    __syncthreads();
    int wr = (w >> 1) * 64, wc = (w & 1) * 64;
    f32x4 acc[4][4];
#pragma unroll
    for (int i = 0; i < 4; i++)
#pragma unroll
        for (int j = 0; j < 4; j++) acc[i][j] = (f32x4){0.f, 0.f, 0.f, 0.f};
#pragma unroll
    for (int kk = 0; kk < 4; ++kk) {
        short8 af[4], bf[4];
#pragma unroll
        for (int rb = 0; rb < 4; ++rb)
            af[rb] = *(const short8*)&CT[(wr + rb * 16 + n16) * 136 + kk * 32 + quad * 8];
#pragma unroll
        for (int cb = 0; cb < 4; ++cb)
            bf[cb] = *(const short8*)&WTs[(wc + cb * 16 + n16) * 136 + kk * 32 + quad * 8];
#pragma unroll
        for (int rb = 0; rb < 4; ++rb)
#pragma unroll
            for (int cb = 0; cb < 4; ++cb)
                acc[rb][cb] = __builtin_amdgcn_mfma_f32_16x16x32_bf16(af[rb], bf[cb], acc[rb][cb], 0, 0, 0);
    }
    __syncthreads();
#pragma unroll
    for (int rb = 0; rb < 4; ++rb)
#pragma unroll
        for (int cb = 0; cb < 4; ++cb) {
            int colb = wc + cb * 16 + n16;
            float bs = bias[head * 128 + colb];
#pragma unroll
            for (int reg = 0; reg < 4; ++reg) {
                int rowb = wr + rb * 16 + quad * 4 + reg;
                unsigned short val = f2bf((acc[rb][cb][reg] + bs) * scale);
                if (mode == 0) CT[rowb * 136 + colb] = val;
                else           CT[colb * 136 + rowb] = val;
            }
        }
    __syncthreads();
    int b = m0 >> 10, n0 = m0 & 1023;
    size_t base = (size_t)(b * 8 + head) * 131072;
    if (mode == 0) {
#pragma unroll
        for (int p = 0; p < 8; ++p) {
            int idx = tid + p * 256;
            int r = idx >> 4, ch = idx & 15;
            *(uint4*)&Out[base + (size_t)(n0 + r) * 128 + ch * 8] = *(const uint4*)&CT[r * 136 + ch * 8];
        }
    } else {
#pragma unroll
        for (int p = 0; p < 8; ++p) {
            int idx = tid + p * 256;
            int r = idx >> 4, ch = idx & 15;
            *(uint4*)&Out[base + (size_t)r * 1024 + n0 + ch * 8] = *(const uint4*)&CT[r * 136 + ch * 8];
        }
    }
}

// ---------------- attention: 36 KB LDS (Sp aliases Ks) -----------------------
// launch_bounds (256,2): VGPR cap 256 -> allocator lands at 128, giving
// 4 waves/SIMD by VGPR and 4 blocks/CU by LDS. (256,4) forced 64 VGPR -> spills.
__global__ __launch_bounds__(256, 2) void k_attn3(const unsigned short* __restrict__ qb,
                                                  const unsigned short* __restrict__ kb,
                                                  const unsigned short* __restrict__ vtb,
                                                  unsigned short* __restrict__ ctxb) {
    __shared__ __align__(16) unsigned short sm[17920];
    unsigned short* Ks = sm;            // [64][136] = 8704 shorts
    unsigned short* Vt = sm + 8704;     // [128][72] = 9216 shorts
    unsigned short* Sp = sm;            // alias of Ks: per-wave [32][68]

    const int tid = threadIdx.x;
    const int w = tid >> 6, lane = tid & 63;
    const int n16 = lane & 15, quad = lane >> 4;
    const int g = blockIdx.x;
    const int bh = g >> 3, tileq = g & 7;

    const unsigned short* Qp = qb + (size_t)bh * 131072 + (size_t)tileq * 128 * 128;
    const unsigned short* Kp = kb + (size_t)bh * 131072;
    const unsigned short* Vp = vtb + (size_t)bh * 131072;

    short8 qf[2][4];
#pragma unroll
    for (int rb = 0; rb < 2; ++rb)
#pragma unroll
        for (int dc = 0; dc < 4; ++dc)
            qf[rb][dc] = *(const short8*)&Qp[(size_t)(w * 32 + rb * 16 + n16) * 128 + dc * 32 + quad * 8];

    float mrun[2][4], lrun[2][4];
#pragma unroll
    for (int rb = 0; rb < 2; ++rb)
#pragma unroll
        for (int r = 0; r < 4; ++r) { mrun[rb][r] = -1e30f; lrun[rb][r] = 0.f; }
    f32x4 O[2][8];
#pragma unroll
    for (int rb = 0; rb < 2; ++rb)
#pragma unroll
        for (int dc = 0; dc < 8; ++dc) O[rb][dc] = (f32x4){0.f, 0.f, 0.f, 0.f};

    for (int kt = 0; kt < 16; ++kt) {
        __syncthreads();                 // prev PV (Sp,Vt reads) done
#pragma unroll
        for (int p = 0; p < 4; ++p) {    // K tile 64x128
            int idx = tid + p * 256;
            int r = idx >> 4, ch = idx & 15;
            *(uint4*)&Ks[r * 136 + ch * 8] = *(const uint4*)&Kp[(size_t)(kt * 64 + r) * 128 + ch * 8];
        }
#pragma unroll
        for (int p = 0; p < 4; ++p) {    // V^T tile 128x64
            int idx = tid + p * 256;
            int r = idx >> 3, ch = idx & 7;
            *(uint4*)&Vt[r * 72 + ch * 8] = *(const uint4*)&Vp[(size_t)r * 1024 + kt * 64 + ch * 8];
        }
        __syncthreads();                 // staged

        f32x4 S[2][4];
#pragma unroll
        for (int rb = 0; rb < 2; ++rb)
#pragma unroll
            for (int kc = 0; kc < 4; ++kc) S[rb][kc] = (f32x4){0.f, 0.f, 0.f, 0.f};
#pragma unroll
        for (int kc = 0; kc < 4; ++kc)
#pragma unroll
            for (int dc = 0; dc < 4; ++dc) {
                short8 kf = *(const short8*)&Ks[(kc * 16 + n16) * 136 + dc * 32 + quad * 8];
                S[0][kc] = __builtin_amdgcn_mfma_f32_16x16x32_bf16(qf[0][dc], kf, S[0][kc], 0, 0, 0);
                S[1][kc] = __builtin_amdgcn_mfma_f32_16x16x32_bf16(qf[1][dc], kf, S[1][kc], 0, 0, 0);
            }

        float alpha[2][4];
#pragma unroll
        for (int rb = 0; rb < 2; ++rb)
#pragma unroll
            for (int reg = 0; reg < 4; ++reg) {
                float mx = fmaxf(fmaxf(S[rb][0][reg], S[rb][1][reg]), fmaxf(S[rb][2][reg], S[rb][3][reg]));
                mx = fmaxf(mx, __shfl_xor(mx, 1));
                mx = fmaxf(mx, __shfl_xor(mx, 2));
                mx = fmaxf(mx, __shfl_xor(mx, 4));
                mx = fmaxf(mx, __shfl_xor(mx, 8));
                float mnew = fmaxf(mrun[rb][reg], mx);
                alpha[rb][reg] = __expf(mrun[rb][reg] - mnew);
                mrun[rb][reg] = mnew;
                float ps = 0.f;
#pragma unroll
                for (int kc = 0; kc < 4; ++kc) {
                    float p = __expf(S[rb][kc][reg] - mnew);
                    S[rb][kc][reg] = p;
                    ps += p;
                }
                ps += __shfl_xor(ps, 1);
                ps += __shfl_xor(ps, 2);
                ps += __shfl_xor(ps, 4);
                ps += __shfl_xor(ps, 8);
                lrun[rb][reg] = lrun[rb][reg] * alpha[rb][reg] + ps;
            }

        __syncthreads();                 // all Ks reads done -> safe to alias Sp
#pragma unroll
        for (int rb = 0; rb < 2; ++rb)
#pragma unroll
            for (int kc = 0; kc < 4; ++kc)
#pragma unroll
                for (int reg = 0; reg < 4; ++reg)
                    Sp[w * 2176 + (rb * 16 + quad * 4 + reg) * 68 + kc * 16 + n16] = f2bf(S[rb][kc][reg]);
        asm volatile("s_waitcnt lgkmcnt(0)" ::: "memory");   // own writes visible

#pragma unroll
        for (int rb = 0; rb < 2; ++rb)
#pragma unroll
            for (int dc = 0; dc < 8; ++dc)
#pragma unroll
                for (int reg = 0; reg < 4; ++reg) O[rb][dc][reg] *= alpha[rb][reg];
#pragma unroll
        for (int kchunk = 0; kchunk < 2; ++kchunk) {
            int off0 = w * 2176 + n16 * 68 + kchunk * 32 + quad * 8;
            short4v a0 = *(const short4v*)&Sp[off0];
            short4v b0 = *(const short4v*)&Sp[off0 + 4];
            short4v a1 = *(const short4v*)&Sp[off0 + 16 * 68];
            short4v b1 = *(const short4v*)&Sp[off0 + 16 * 68 + 4];
            short8 pf0, pf1;
#pragma unroll
            for (int j = 0; j < 4; ++j) {
                pf0[j] = a0[j]; pf0[j + 4] = b0[j];
                pf1[j] = a1[j]; pf1[j + 4] = b1[j];
            }
#pragma unroll
            for (int dc = 0; dc < 8; ++dc) {
                short8 vf = *(const short8*)&Vt[(dc * 16 + n16) * 72 + kchunk * 32 + quad * 8];
                O[0][dc] = __builtin_amdgcn_mfma_f32_16x16x32_bf16(pf0, vf, O[0][dc], 0, 0, 0);
                O[1][dc] = __builtin_amdgcn_mfma_f32_16x16x32_bf16(pf1, vf, O[1][dc], 0, 0, 0);
            }
        }
    }

    __syncthreads();
    unsigned short* Ct = sm;    // [128][136]
#pragma unroll
    for (int rb = 0; rb < 2; ++rb)
#pragma unroll
        for (int reg = 0; reg < 4; ++reg) {
            float inv = 1.f / lrun[rb][reg];
            int row = w * 32 + rb * 16 + quad * 4 + reg;
#pragma unroll
            for (int dc = 0; dc < 8; ++dc)
                Ct[row * 136 + dc * 16 + n16] = f2bf(O[rb][dc][reg] * inv);
        }
    __syncthreads();
    unsigned short* Outp = ctxb + (size_t)bh * 131072 + (size_t)tileq * 128 * 128;
#pragma unroll
    for (int p = 0; p < 8; ++p) {
        int idx = tid + p * 256;
        int r = idx >> 4, ch = idx & 15;
        *(uint4*)&Outp[(size_t)r * 128 + ch * 8] = *(const uint4*)&Ct[r * 136 + ch * 8];
    }
}

// ---------------- hgT = (ctx @ WoG + boG)^T  (K=1024, Wg folded) -------------
__global__ __launch_bounds__(256) void k_proj_og(const unsigned short* __restrict__ Ctxb,
                                                 const unsigned short* __restrict__ WoGT,
                                                 const float* __restrict__ boG,
                                                 unsigned short* __restrict__ HgT) {
    __shared__ __align__(16) unsigned short sm[64 * 72 + 128 * 72];
    unsigned short* As = sm;
    unsigned short* Bs = sm + 64 * 72;
    int tid = threadIdx.x;
    int m0 = blockIdx.x * 64;
    int b = m0 >> 10, n0 = m0 & 1023;
    int w = tid >> 6, lane = tid & 63, n16 = lane & 15, quad = lane >> 4;
    int wr = (w & 1) * 32, wc = (w >> 1) * 64;
    f32x4 acc[2][4];
#pragma unroll
    for (int i = 0; i < 2; i++)
#pragma unroll
        for (int j = 0; j < 4; j++) acc[i][j] = (f32x4){0.f, 0.f, 0.f, 0.f};
    for (int kt = 0; kt < 16; ++kt) {
        __syncthreads();
        int hh = kt >> 1, d0 = (kt & 1) * 64;
#pragma unroll
        for (int p = 0; p < 2; ++p) {
            int idx = tid + p * 256;
            int r = idx >> 3, ch = idx & 7;
            *(uint4*)&As[r * 72 + ch * 8] =
                *(const uint4*)&Ctxb[((size_t)(b * 8 + hh) * 1024 + n0 + r) * 128 + d0 + ch * 8];
        }
#pragma unroll
        for (int p = 0; p < 4; ++p) {
            int idx = tid + p * 256;
            int r = idx >> 3, ch = idx & 7;
            *(uint4*)&Bs[r * 72 + ch * 8] = *(const uint4*)&WoGT[(size_t)r * 1024 + kt * 64 + ch * 8];
        }
        __syncthreads();
#pragma unroll
        for (int kk = 0; kk < 2; ++kk) {
            short8 af0 = *(const short8*)&As[(wr + n16) * 72 + kk * 32 + quad * 8];
            short8 af1 = *(const short8*)&As[(wr + 16 + n16) * 72 + kk * 32 + quad * 8];
#pragma unroll
            for (int cb = 0; cb < 4; ++cb) {
                short8 bf = *(const short8*)&Bs[(wc + cb * 16 + n16) * 72 + kk * 32 + quad * 8];
                acc[0][cb] = __builtin_amdgcn_mfma_f32_16x16x32_bf16(af0, bf, acc[0][cb], 0, 0, 0);
                acc[1][cb] = __builtin_amdgcn_mfma_f32_16x16x32_bf16(af1, bf, acc[1][cb], 0, 0, 0);
            }
        }
    }
    __syncthreads();
    unsigned short* Ct = sm;    // [128 cols][80]
#pragma unroll
    for (int rb = 0; rb < 2; ++rb)
#pragma unroll
        for (int cb = 0; cb < 4; ++cb) {
            int col = wc + cb * 16 + n16;
            float bs = boG[col];
#pragma unroll
            for (int reg = 0; reg < 4; ++reg)
                Ct[col * 80 + wr + rb * 16 + quad * 4 + reg] = f2bf(acc[rb][cb][reg] + bs);
        }
    __syncthreads();
#pragma unroll
    for (int p = 0; p < 4; ++p) {
        int idx = tid + p * 256;
        int c = idx >> 3, ch = idx & 7;
        *(uint4*)&HgT[(size_t)b * 131072 + (size_t)c * 1024 + n0 + ch * 8] =
            *(const uint4*)&Ct[c * 80 + ch * 8];
    }
}

// ---------------- feat = relu(A_t @ hg) fused with row-normalize -> bf16 -----
__global__ __launch_bounds__(256) void k_at_norm(const float* __restrict__ At,
                                                 const unsigned short* __restrict__ HgT,
                                                 unsigned short* __restrict__ Nb) {
    __shared__ __align__(16) char smc[64 * 136 * 4];
    unsigned short* As = (unsigned short*)smc;            // [64][72]
    unsigned short* Bs = (unsigned short*)smc + 64 * 72;  // [128][72]
    int tid = threadIdx.x;
    int bz = blockIdx.z;
    int m0 = blockIdx.x * 64;
    int w = tid >> 6, lane = tid & 63, n16 = lane & 15, quad = lane >> 4;
    int wr = (w & 1) * 32, wc = (w >> 1) * 64;
    f32x4 acc[2][4];
#pragma unroll
    for (int i = 0; i < 2; i++)
#pragma unroll
        for (int j = 0; j < 4; j++) acc[i][j] = (f32x4){0.f, 0.f, 0.f, 0.f};
    for (int kt = 0; kt < 16; ++kt) {
        __syncthreads();
#pragma unroll
        for (int p = 0; p < 2; ++p) {
            int idx = tid + p * 256;
            int r = idx >> 3, ch = idx & 7;
            const float* s = At + (size_t)bz * 1048576 + (size_t)(m0 + r) * 1024 + kt * 64 + ch * 8;
            float4 x = *(const float4*)s;
            float4 y = *(const float4*)(s + 4);
            uint4 o;
            o.x = pack2(x.x, x.y); o.y = pack2(x.z, x.w);
            o.z = pack2(y.x, y.y); o.w = pack2(y.z, y.w);
            *(uint4*)&As[r * 72 + ch * 8] = o;
        }
#pragma unroll
        for (int p = 0; p < 4; ++p) {
            int idx = tid + p * 256;
            int r = idx >> 3, ch = idx & 7;
            *(uint4*)&Bs[r * 72 + ch * 8] =
                *(const uint4*)&HgT[(size_t)bz * 131072 + (size_t)r * 1024 + kt * 64 + ch * 8];
        }
        __syncthreads();
#pragma unroll
        for (int kk = 0; kk < 2; ++kk) {
            short8 af0 = *(const short8*)&As[(wr + n16) * 72 + kk * 32 + quad * 8];
            short8 af1 = *(const short8*)&As[(wr + 16 + n16) * 72 + kk * 32 + quad * 8];
#pragma unroll
            for (int cb = 0; cb < 4; ++cb) {
                short8 bf = *(const short8*)&Bs[(wc + cb * 16 + n16) * 72 + kk * 32 + quad * 8];
                acc[0][cb] = __builtin_amdgcn_mfma_f32_16x16x32_bf16(af0, bf, acc[0][cb], 0, 0, 0);
                acc[1][cb] = __builtin_amdgcn_mfma_f32_16x16x32_bf16(af1, bf, acc[1][cb], 0, 0, 0);
            }
        }
    }
    __syncthreads();
    float* F = (float*)smc;    // [64][136]
#pragma unroll
    for (int rb = 0; rb < 2; ++rb)
#pragma unroll
        for (int cb = 0; cb < 4; ++cb) {
            int col = wc + cb * 16 + n16;
#pragma unroll
            for (int reg = 0; reg < 4; ++reg)
                F[(wr + rb * 16 + quad * 4 + reg) * 136 + col] = fmaxf(acc[rb][cb][reg], 0.f);
        }
    __syncthreads();
    // normalize: 4 lanes per row, 32 cols each
    int r = tid >> 2, l4 = tid & 3;
    float vals[32];
    float s = 0.f;
#pragma unroll
    for (int u = 0; u < 32; ++u) { vals[u] = F[r * 136 + l4 * 32 + u]; s += vals[u]; }
    s += __shfl_xor(s, 1);
    s += __shfl_xor(s, 2);
    float mu = s * (1.f / 128.f);
    float sq = 0.f;
#pragma unroll
    for (int u = 0; u < 32; ++u) { float d = vals[u] - mu; vals[u] = d; sq += d * d; }
    sq += __shfl_xor(sq, 1);
    sq += __shfl_xor(sq, 2);
    float inv = 1.f / (sqrtf(sq * (1.f / 127.f)) + 1e-8f);
    size_t rowb = ((size_t)bz * 1024 + m0 + r) * 128 + l4 * 32;
#pragma unroll
    for (int gch = 0; gch < 4; ++gch) {
        uint4 o;
        o.x = pack2(vals[gch * 8 + 0] * inv, vals[gch * 8 + 1] * inv);
        o.y = pack2(vals[gch * 8 + 2] * inv, vals[gch * 8 + 3] * inv);
        o.z = pack2(vals[gch * 8 + 4] * inv, vals[gch * 8 + 5] * inv);
        o.w = pack2(vals[gch * 8 + 6] * inv, vals[gch * 8 + 7] * inv);
        *(uint4*)&Nb[rowb + gch * 8] = o;
    }
}

// ---------------- out[b] = norm @ norm^T / 128, LDS-bounced stores -----------
__global__ __launch_bounds__(256) void k_corr(const unsigned short* __restrict__ Nb,
                                              float* __restrict__ Out) {
    __shared__ __align__(16) unsigned short sm[2 * 128 * 136];
    unsigned short* Ar = sm;
    unsigned short* Br = sm + 128 * 136;
    int tid = threadIdx.x;
    int bz = blockIdx.z;
    int n0 = blockIdx.x * 128, m0 = blockIdx.y * 128;
    const unsigned short* base = Nb + (size_t)bz * 131072;
    int w = tid >> 6, lane = tid & 63, n16 = lane & 15, quad = lane >> 4;
#pragma unroll
    for (int p = 0; p < 8; ++p) {
        int idx = tid + p * 256;
        int r = idx >> 4, ch = idx & 15;
        *(uint4*)&Ar[r * 136 + ch * 8] = *(const uint4*)&base[(size_t)(n0 + r) * 128 + ch * 8];
        *(uint4*)&Br[r * 136 + ch * 8] = *(const uint4*)&base[(size_t)(m0 + r) * 128 + ch * 8];
    }
    __syncthreads();
    int wr = (w >> 1) * 64, wc = (w & 1) * 64;
    f32x4 acc[4][4];
#pragma unroll
    for (int i = 0; i < 4; i++)
#pragma unroll
        for (int j = 0; j < 4; j++) acc[i][j] = (f32x4){0.f, 0.f, 0.f, 0.f};
#pragma unroll
    for (int kk = 0; kk < 4; ++kk) {
        short8 af[4], bf[4];
#pragma unroll
        for (int rb = 0; rb < 4; ++rb)
            af[rb] = *(const short8*)&Ar[(wr + rb * 16 + n16) * 136 + kk * 32 + quad * 8];
#pragma unroll
        for (int cb = 0; cb < 4; ++cb)
            bf[cb] = *(const short8*)&Br[(wc + cb * 16 + n16) * 136 + kk * 32 + quad * 8];
#pragma unroll
        for (int rb = 0; rb < 4; ++rb)
#pragma unroll
            for (int cb = 0; cb < 4; ++cb)
                acc[rb][cb] = __builtin_amdgcn_mfma_f32_16x16x32_bf16(af[rb], bf[cb], acc[rb][cb], 0, 0, 0);
    }
    __syncthreads();
    float* F = (float*)sm;   // [64][136] fp32 bounce, two row-passes
    float* Op = Out + (size_t)bz * 1048576;
#pragma unroll
    for (int pass = 0; pass < 2; ++pass) {
        if ((w >> 1) == pass) {
#pragma unroll
            for (int rb = 0; rb < 4; ++rb)
#pragma unroll
                for (int cb = 0; cb < 4; ++cb) {
                    int col = wc + cb * 16 + n16;
#pragma unroll
                    for (int reg = 0; reg < 4; ++reg)
                        F[(rb * 16 + quad * 4 + reg) * 136 + col] = acc[rb][cb][reg] * 0.0078125f;
                }
        }
        __syncthreads();
#pragma unroll
        for (int i = 0; i < 8; ++i) {
            int idx = tid + i * 256;
            int r = idx >> 5, ch = idx & 31;
            *(float4*)&Op[(size_t)(n0 + pass * 64 + r) * 1024 + m0 + ch * 4] =
                *(const float4*)&F[r * 136 + ch * 4];
        }
        __syncthreads();
    }
}

extern "C" void kernel_launch(void* const* d_in, const int* in_sizes, int n_in,
                              void* d_out, int out_size, void* d_ws, size_t ws_size,
                              hipStream_t stream) {
    const float* A_t = (const float*)d_in[0];
    const float* F_c = (const float*)d_in[1];
    const int*   t   = (const int*)d_in[2];
    const float* Wq  = (const float*)d_in[3];
    const float* bq  = (const float*)d_in[4];
    const float* Wk  = (const float*)d_in[5];
    const float* bk  = (const float*)d_in[6];
    const float* Wv  = (const float*)d_in[7];
    const float* bv  = (const float*)d_in[8];
    const float* Wo  = (const float*)d_in[9];
    const float* bo  = (const float*)d_in[10];
    const float* Wg  = (const float*)d_in[11];
    float* out = (float*)d_out;
    char* ws = (char*)d_ws;

    unsigned short* cb   = (unsigned short*)(ws);                 //  4 MB
    unsigned short* qb   = (unsigned short*)(ws + 4194304);       // 33.5 MB
    unsigned short* kbuf = (unsigned short*)(ws + 37748736);      // 33.5 MB
    unsigned short* vtb  = (unsigned short*)(ws + 71303168);      // 33.5 MB
    unsigned short* ctxb = (unsigned short*)(ws + 104857600);     // 33.5 MB
    unsigned short* hgT  = (unsigned short*)(ws + 138412032);     //  4 MB
    unsigned short* nb   = (unsigned short*)(ws + 142606336);     //  4 MB
    unsigned short* WqT  = (unsigned short*)(ws + 146800640);
    unsigned short* WkT  = (unsigned short*)(ws + 147062784);
    unsigned short* WvT  = (unsigned short*)(ws + 147324928);
    unsigned short* WoGT = (unsigned short*)(ws + 147587072);
    float*          boG  = (float*)         (ws + 147849216);

    const float qscale = 0.08838834764831845f;   // 1/sqrt(128)

    k_prep<<<512, 256, 0, stream>>>(Wq, Wk, Wv, Wo, Wg, bo, WqT, WkT, WvT, WoGT, boG);
    k_embed<<<1024, 256, 0, stream>>>(F_c, t, cb);
    k_proj<<<dim3(128, 8), 256, 0, stream>>>(cb, WqT, bq, qb,   qscale, 0);
    k_proj<<<dim3(128, 8), 256, 0, stream>>>(cb, WkT, bk, kbuf, 1.f,    0);
    k_proj<<<dim3(128, 8), 256, 0, stream>>>(cb, WvT, bv, vtb,  1.f,    1);
    k_attn3<<<1024, 256, 0, stream>>>(qb, kbuf, vtb, ctxb);
    k_proj_og<<<256, 256, 0, stream>>>(ctxb, WoGT, boG, hgT);
    k_at_norm<<<dim3(16, 1, 16), 256, 0, stream>>>(A_t, hgT, nb);
    k_corr<<<dim3(8, 8, 16), 256, 0, stream>>>(nb, out);
}